// Round 3
// baseline (243.611 us; speedup 1.0000x reference)
//
#include <hip/hip_runtime.h>
#include <math.h>

#define DIMS 128
#define KNEG 256
#define INV_TEMP 20.0f   // 1 / 0.05
#define EPSN 1e-12f

// One block (256 threads = 8 half-waves of 32 lanes) per output row n.
// Packed butterfly reduce: 12 cross-lane ops per 2 rows instead of 20.
// Final weighted-mean fused via last-block-done (int atomic, deterministic).
__global__ __launch_bounds__(256, 8) void ssl_fused_kernel(
    const float* __restrict__ out_emb,   // [N, 128]
    const float* __restrict__ table,     // [M, 128] raw (unnormalized)
    const float* __restrict__ w,         // [N]
    const int*   __restrict__ tgt,       // [N]
    const int*   __restrict__ negs,      // [N, 256]
    float*       __restrict__ loss_ws,   // [N] scratch: loss_per * w
    unsigned*    __restrict__ cnt,       // [1] completion counter (pre-zeroed)
    float*       __restrict__ out,       // [1] final loss
    int N, int max_row)
{
    const int t    = threadIdx.x;
    const int hw   = t >> 5;   // half-wave id 0..7
    const int lane = t & 31;   // lane in half-wave

    __shared__ __align__(16) float q_lds[DIMS];
    __shared__ float logits[KNEG + 1];
    __shared__ int   nid[KNEG];
    __shared__ float red[8];
    __shared__ unsigned sh_order;

    for (int n = blockIdx.x; n < N; n += gridDim.x) {
        const float wn = w[n];                 // uniform per block-iteration
        if (wn == 0.0f) {                      // contributes 0 to weighted sum
            if (t == 0) loss_ws[n] = 0.0f;
            continue;
        }

        // ---- normalize q row into LDS; stage neg ids ----
        float x = (t < DIMS) ? out_emb[(size_t)n * DIMS + t] : 0.0f;
        float ss = x * x;
        #pragma unroll
        for (int m = 1; m < 64; m <<= 1) ss += __shfl_xor(ss, m, 64);
        if ((t & 63) == 0) red[t >> 6] = ss;
        nid[t] = negs[(size_t)n * KNEG + t];
        __syncthreads();
        const float inv_qn = 1.0f / fmaxf(sqrtf(red[0] + red[1]), EPSN);
        if (t < DIMS) q_lds[t] = x * inv_qn;
        __syncthreads();

        const float4 qv = *(const float4*)(q_lds + lane * 4);
        const int tgtn = tgt[n];

        auto rowp = [&](int id) -> const float4* {
            int i = id - 1; i = i < 0 ? 0 : (i > max_row ? max_row : i);
            return (const float4*)(table + (size_t)i * DIMS);
        };

        // tail row (j == 256): issue load early, reduce after main loop
        float4 et;
        if (hw == 0) et = rowp(nid[KNEG - 1])[lane];

        // ---- main gathers: 16 pairs per half-wave, packed reduce ----
        #pragma unroll
        for (int p = 0; p < 16; ++p) {
            const int j1  = hw + (p << 4);
            const int id1 = (p == 0 && hw == 0) ? tgtn : nid[j1 - 1];
            const int id2 = nid[j1 + 7];
            const float4 a = rowp(id1)[lane];
            const float4 b = rowp(id2)[lane];
            float dq1 = qv.x*a.x + qv.y*a.y + qv.z*a.z + qv.w*a.w;
            float de1 = a.x*a.x + a.y*a.y + a.z*a.z + a.w*a.w;
            float dq2 = qv.x*b.x + qv.y*b.y + qv.z*b.z + qv.w*b.w;
            float de2 = b.x*b.x + b.y*b.y + b.z*b.z + b.w*b.w;
            // fold to 8 partials each (xor16, xor8)
            dq1 += __shfl_xor(dq1, 16, 64); de1 += __shfl_xor(de1, 16, 64);
            dq2 += __shfl_xor(dq2, 16, 64); de2 += __shfl_xor(de2, 16, 64);
            dq1 += __shfl_xor(dq1, 8, 64);  de1 += __shfl_xor(de1, 8, 64);
            dq2 += __shfl_xor(dq2, 8, 64);  de2 += __shfl_xor(de2, 8, 64);
            // select into 8-lane quarters: 0-7 dq1, 8-15 de1, 16-23 dq2, 24-31 de2
            const int q = (lane >> 3) & 3;
            float v = (q == 0) ? dq1 : (q == 1) ? de1 : (q == 2) ? dq2 : de2;
            v += __shfl_xor(v, 1, 64);
            v += __shfl_xor(v, 2, 64);
            v += __shfl_xor(v, 4, 64);
            const float u = __shfl_xor(v, 8, 64);   // lane0: de1, lane16: de2
            if (lane == 0)  logits[j1]     = v / fmaxf(sqrtf(u), EPSN) * INV_TEMP;
            if (lane == 16) logits[j1 + 8] = v / fmaxf(sqrtf(u), EPSN) * INV_TEMP;
        }

        if (hw == 0) {   // reduce the tail row (packed 2-value)
            float dq = qv.x*et.x + qv.y*et.y + qv.z*et.z + qv.w*et.w;
            float de = et.x*et.x + et.y*et.y + et.z*et.z + et.w*et.w;
            dq += __shfl_xor(dq, 16, 64); de += __shfl_xor(de, 16, 64);
            dq += __shfl_xor(dq, 8, 64);  de += __shfl_xor(de, 8, 64);
            float v = (lane & 8) ? de : dq;   // lanes 0-7 dq, 8-15 de (rep. x2)
            v += __shfl_xor(v, 1, 64);
            v += __shfl_xor(v, 2, 64);
            v += __shfl_xor(v, 4, 64);
            const float u = __shfl_xor(v, 8, 64);
            if (lane == 0) logits[KNEG] = v / fmaxf(sqrtf(u), EPSN) * INV_TEMP;
        }
        __syncthreads();

        // ---- stable LSE over 257 logits ----
        float mx = logits[t];
        if (t == 0) mx = fmaxf(mx, logits[KNEG]);
        #pragma unroll
        for (int m = 1; m < 64; m <<= 1) mx = fmaxf(mx, __shfl_xor(mx, m, 64));
        if ((t & 63) == 0) red[t >> 6] = mx;
        __syncthreads();
        if (t == 0) red[4] = fmaxf(fmaxf(red[0], red[1]), fmaxf(red[2], red[3]));
        __syncthreads();
        mx = red[4];

        float pp = expf(logits[t] - mx);
        if (t == 0) pp += expf(logits[KNEG] - mx);
        #pragma unroll
        for (int m = 1; m < 64; m <<= 1) pp += __shfl_xor(pp, m, 64);
        if ((t & 63) == 0) red[t >> 6] = pp;
        __syncthreads();
        if (t == 0) {
            const float s   = red[0] + red[1] + red[2] + red[3];
            const float lse = mx + logf(s);
            loss_ws[n] = (lse - logits[0]) * wn;   // loss_per * w
        }
        __syncthreads();   // protect shared buffers before next iteration
    }

    // ---- last-block-done: fused deterministic weighted mean ----
    if (t == 0) {
        __threadfence();                       // release our loss_ws stores
        sh_order = atomicAdd(cnt, 1u);         // device-scope
    }
    __syncthreads();
    if (sh_order == (unsigned)(gridDim.x - 1)) {
        __threadfence();                       // acquire others' stores
        float sl = 0.0f, sw = 0.0f;
        for (int i = t; i < N; i += 256) { sl += loss_ws[i]; sw += w[i]; }
        #pragma unroll
        for (int m = 1; m < 64; m <<= 1) {
            sl += __shfl_xor(sl, m, 64);
            sw += __shfl_xor(sw, m, 64);
        }
        if ((t & 63) == 0) { red[t >> 6] = sl; red[4 + (t >> 6)] = sw; }
        __syncthreads();
        if (t == 0) {
            const float SL = red[0] + red[1] + red[2] + red[3];
            const float SW = red[4] + red[5] + red[6] + red[7];
            out[0] = SL / SW;
        }
    }
}

extern "C" void kernel_launch(void* const* d_in, const int* in_sizes, int n_in,
                              void* d_out, int out_size, void* d_ws, size_t ws_size,
                              hipStream_t stream) {
    const float* out_emb = (const float*)d_in[0];   // [16,256,128]
    const float* table   = (const float*)d_in[1];   // [1000001,128]
    const float* w       = (const float*)d_in[2];   // [16,256]
    const int*   tgt     = (const int*)d_in[3];     // [16,256]
    const int*   negs    = (const int*)d_in[4];     // [4096,256]

    const int N = in_sizes[2];                       // 4096
    const int rows = in_sizes[1] / DIMS;             // 1000001
    const int max_row = rows - 1;

    // ws layout: [0:4) completion counter, [64 : 64+4N) loss scratch
    unsigned* cnt  = (unsigned*)d_ws;
    float* loss_ws = (float*)((char*)d_ws + 64);

    hipMemsetAsync(cnt, 0, sizeof(unsigned), stream);
    ssl_fused_kernel<<<N, 256, 0, stream>>>(out_emb, table, w, tgt, negs,
                                            loss_ws, cnt, (float*)d_out,
                                            N, max_row);
}

// Round 4
// 133.059 us; speedup vs baseline: 1.8309x; 1.8309x over previous
//
#include <hip/hip_runtime.h>
#include <math.h>

#define DIMS 128
#define KNEG 256
#define INV_TEMP 20.0f   // 1 / 0.05
#define EPSN 1e-12f
#define PASSES 3

// Grid = N/2 blocks (2048) x 256 threads = exactly the co-resident capacity
// at 8 blocks/CU. Each block owns rows (b, b + N/2). The table id-range is
// split into PASSES chunks (~171 MB each < 256 MB L3); all blocks gather
// pass p's ids before pass p+1 (approximate lockstep via co-residency), so
// duplicate row references hit L3 instead of thrashing it.
__global__ __launch_bounds__(256, 8) void ssl_row_kernel(
    const float* __restrict__ out_emb,   // [N, 128]
    const float* __restrict__ table,     // [M, 128] raw (unnormalized)
    const float* __restrict__ w,         // [N]
    const int*   __restrict__ tgt,       // [N]
    const int*   __restrict__ negs,      // [N, 256]
    float*       __restrict__ loss_out,  // [N] = loss_per * w
    int N, int max_row)                  // max_row = M-1
{
    const int t    = threadIdx.x;
    const int hw   = t >> 5;   // half-wave 0..7
    const int lane = t & 31;
    const int n0   = blockIdx.x;
    const int n1   = blockIdx.x + (N >> 1);

    __shared__ __align__(16) float q_lds[2][DIMS];
    __shared__ float logits[2][KNEG + 1];
    __shared__ int   nid[2][KNEG];
    __shared__ float red[8];

    const float w0 = w[n0], w1 = w[n1];
    const bool  v0 = (w0 != 0.0f), v1 = (w1 != 0.0f);
    if (t == 0) {
        if (!v0) loss_out[n0] = 0.0f;
        if (!v1) loss_out[n1] = 0.0f;
    }
    if (!v0 && !v1) return;

    // ---- stage q rows (threads 0-127 -> row0, 128-255 -> row1) + neg ids ----
    {
        const int r  = t >> 7;
        const int d  = t & 127;
        const int nr = r ? n1 : n0;
        const float x = out_emb[(size_t)nr * DIMS + d];
        float ss = x * x;
        #pragma unroll
        for (int m = 1; m < 64; m <<= 1) ss += __shfl_xor(ss, m, 64);
        if ((t & 63) == 0) red[t >> 6] = ss;
        nid[0][t] = negs[(size_t)n0 * KNEG + t];
        nid[1][t] = negs[(size_t)n1 * KNEG + t];
        __syncthreads();
        const float inv = 1.0f / fmaxf(sqrtf(red[2 * r] + red[2 * r + 1]), EPSN);
        q_lds[r][d] = x * inv;
        __syncthreads();
    }

    const float4 qv0 = *(const float4*)(&q_lds[0][lane * 4]);
    const float4 qv1 = *(const float4*)(&q_lds[1][lane * 4]);
    const int tgt0 = tgt[n0], tgt1 = tgt[n1];
    const long long M = (long long)max_row + 1;

    // per-element gather + packed {dq,de} butterfly reduce (8 shfl/elem)
    auto do_elem = [&](int r, int idx, int j, const float4& qv) {
        const float4 e = ((const float4*)(table + (size_t)idx * DIMS))[lane];
        float dq = qv.x*e.x + qv.y*e.y + qv.z*e.z + qv.w*e.w;
        float de = e.x*e.x + e.y*e.y + e.z*e.z + e.w*e.w;
        dq += __shfl_xor(dq, 16, 64); de += __shfl_xor(de, 16, 64);
        dq += __shfl_xor(dq, 8, 64);  de += __shfl_xor(de, 8, 64);
        float v = (lane & 8) ? de : dq;   // lanes0-7 dq partials, 8-15 de partials
        v += __shfl_xor(v, 1, 64);
        v += __shfl_xor(v, 2, 64);
        v += __shfl_xor(v, 4, 64);
        const float u = __shfl_xor(v, 8, 64);   // lane0 <- de total
        if (lane == 0) logits[r][j] = v / fmaxf(sqrtf(u), EPSN) * INV_TEMP;
    };

    for (int pass = 0; pass < PASSES; ++pass) {
        const int lo = (int)(( (long long)pass      * M) / PASSES);
        const int hi = (int)(( (long long)(pass + 1)* M) / PASSES);
        #pragma unroll 1
        for (int r = 0; r < 2; ++r) {
            if (r ? !v1 : !v0) continue;
            const float4 qv = r ? qv1 : qv0;
            const int tg = r ? tgt1 : tgt0;
            #pragma unroll 4
            for (int i = 0; i < 32; ++i) {
                const int j  = (hw << 5) + i;
                const int id = (j == 0) ? tg : nid[r][j - 1];
                int idx = id - 1; idx = idx < 0 ? 0 : (idx > max_row ? max_row : idx);
                if (idx >= lo && idx < hi) do_elem(r, idx, j, qv);
            }
            if (hw == 7) {   // tail logit j == 256
                const int id = nid[r][KNEG - 1];
                int idx = id - 1; idx = idx < 0 ? 0 : (idx > max_row ? max_row : idx);
                if (idx >= lo && idx < hi) do_elem(r, idx, KNEG, qv);
            }
        }
    }
    __syncthreads();

    // ---- stable LSE per row over 257 logits ----
    #pragma unroll 1
    for (int r = 0; r < 2; ++r) {
        if (r ? !v1 : !v0) continue;    // block-uniform branch
        float mx = logits[r][t];
        if (t == 0) mx = fmaxf(mx, logits[r][KNEG]);
        #pragma unroll
        for (int m = 1; m < 64; m <<= 1) mx = fmaxf(mx, __shfl_xor(mx, m, 64));
        if ((t & 63) == 0) red[t >> 6] = mx;
        __syncthreads();
        if (t == 0) red[4] = fmaxf(fmaxf(red[0], red[1]), fmaxf(red[2], red[3]));
        __syncthreads();
        mx = red[4];

        float pp = expf(logits[r][t] - mx);
        if (t == 0) pp += expf(logits[r][KNEG] - mx);
        #pragma unroll
        for (int m = 1; m < 64; m <<= 1) pp += __shfl_xor(pp, m, 64);
        if ((t & 63) == 0) red[t >> 6] = pp;
        __syncthreads();
        if (t == 0) {
            const float s   = red[0] + red[1] + red[2] + red[3];
            const float lse = mx + logf(s);
            loss_out[r ? n1 : n0] = (lse - logits[r][0]) * (r ? w1 : w0);
        }
        __syncthreads();   // red[] reused next row
    }
}

// Deterministic final reduction: sum(loss*w) / sum(w)
__global__ __launch_bounds__(256) void ssl_reduce_kernel(
    const float* __restrict__ loss,  // [N]
    const float* __restrict__ w,     // [N]
    float* __restrict__ out, int n)
{
    __shared__ float red[8];
    const int t = threadIdx.x;
    float sl = 0.0f, sw = 0.0f;
    for (int i = t; i < n; i += 256) { sl += loss[i]; sw += w[i]; }
    #pragma unroll
    for (int m = 1; m < 64; m <<= 1) {
        sl += __shfl_xor(sl, m, 64);
        sw += __shfl_xor(sw, m, 64);
    }
    if ((t & 63) == 0) { red[t >> 6] = sl; red[4 + (t >> 6)] = sw; }
    __syncthreads();
    if (t == 0) {
        const float SL = red[0] + red[1] + red[2] + red[3];
        const float SW = red[4] + red[5] + red[6] + red[7];
        out[0] = SL / SW;
    }
}

extern "C" void kernel_launch(void* const* d_in, const int* in_sizes, int n_in,
                              void* d_out, int out_size, void* d_ws, size_t ws_size,
                              hipStream_t stream) {
    const float* out_emb = (const float*)d_in[0];   // [16,256,128]
    const float* table   = (const float*)d_in[1];   // [1000001,128]
    const float* w       = (const float*)d_in[2];   // [16,256]
    const int*   tgt     = (const int*)d_in[3];     // [16,256]
    const int*   negs    = (const int*)d_in[4];     // [4096,256]

    const int N = in_sizes[2];                       // 4096
    const int rows = in_sizes[1] / DIMS;             // 1000001
    const int max_row = rows - 1;

    float* loss_ws = (float*)d_ws;                   // N floats

    ssl_row_kernel<<<N / 2, 256, 0, stream>>>(out_emb, table, w, tgt, negs,
                                              loss_ws, N, max_row);
    ssl_reduce_kernel<<<1, 256, 0, stream>>>(loss_ws, w, (float*)d_out, N);
}

// Round 5
// 127.284 us; speedup vs baseline: 1.9139x; 1.0454x over previous
//
#include <hip/hip_runtime.h>
#include <math.h>

#define DIMS 128
#define KNEG 256
#define NLOG 257             // logits per row (target + 256 negatives)
#define INV_TEMP 20.0f       // 1 / 0.05
#define EPSN 1e-12f
#define SENT 0x7FFFFFFFu
#define SORTN 1024           // 2 rows x 257 items, padded for bitonic

// Persistent-ish grid: N/2 = 2048 blocks = exactly resident capacity at
// 8 blocks/CU. Block b owns rows (b, b+N/2). All 514 gather items are
// sorted by table idx (key = idx<<10 | r<<9 | j); each half-wave streams
// its subsequence in ascending-idx order with a 2-deep load pipeline.
// Device-wide this sweeps the table front-to-back: duplicate rows hit L3,
// DRAM sees a compact moving window, and the memory pipe stays fed.
__global__ __launch_bounds__(256, 8) void ssl_sorted_kernel(
    const float* __restrict__ out_emb,   // [N, 128]
    const float* __restrict__ table,     // [M, 128] raw
    const float* __restrict__ w,         // [N]
    const int*   __restrict__ tgt,       // [N]
    const int*   __restrict__ negs,      // [N, 256]
    float*       __restrict__ loss_out,  // [N] = loss_per * w
    int N, int max_row)
{
    const int t    = threadIdx.x;
    const int hw   = t >> 5;
    const int lane = t & 31;
    const int n0   = blockIdx.x;
    const int n1   = blockIdx.x + (N >> 1);

    __shared__ __align__(16) float q_lds[2][DIMS];
    __shared__ unsigned keys[SORTN];
    __shared__ float logits[2][NLOG];
    __shared__ float red[8];

    const float w0 = w[n0], w1 = w[n1];
    const bool  v0 = (w0 != 0.0f), v1 = (w1 != 0.0f);
    if (t == 0) {
        if (!v0) loss_out[n0] = 0.0f;
        if (!v1) loss_out[n1] = 0.0f;
    }
    if (!v0 && !v1) return;   // block-uniform

    // ---- normalize q rows: threads 0-127 -> row0, 128-255 -> row1 ----
    {
        const int r  = t >> 7;
        const int d  = t & 127;
        const int nr = r ? n1 : n0;
        const float x = out_emb[(size_t)nr * DIMS + d];
        float ss = x * x;
        #pragma unroll
        for (int m = 1; m < 64; m <<= 1) ss += __shfl_xor(ss, m, 64);
        if ((t & 63) == 0) red[t >> 6] = ss;
        // pad sort keys while we're here
        keys[t] = SENT; keys[t + 256] = SENT; keys[t + 512] = SENT; keys[t + 768] = SENT;
        __syncthreads();
        const float inv = 1.0f / fmaxf(sqrtf(red[2 * r] + red[2 * r + 1]), EPSN);
        q_lds[r][d] = x * inv;
    }

    // ---- build sort keys: key = idx<<10 | r<<9 | j  (idx pre-clamped) ----
    {
        #pragma unroll
        for (int r = 0; r < 2; ++r) {
            if (r ? !v1 : !v0) continue;
            const int nr = r ? n1 : n0;
            int id = (t == 0) ? tgt[nr] : negs[(size_t)nr * KNEG + t - 1];
            int idx = id - 1; idx = idx < 0 ? 0 : (idx > max_row ? max_row : idx);
            keys[r * NLOG + t] = ((unsigned)idx << 10) | ((unsigned)r << 9) | (unsigned)t;
            if (t == 0) {   // j == 256
                int id2 = negs[(size_t)nr * KNEG + KNEG - 1];
                int ix2 = id2 - 1; ix2 = ix2 < 0 ? 0 : (ix2 > max_row ? max_row : ix2);
                keys[r * NLOG + 256] = ((unsigned)ix2 << 10) | ((unsigned)r << 9) | 256u;
            }
        }
    }

    // ---- bitonic sort 1024 (ascending) ----
    for (unsigned k = 2; k <= SORTN; k <<= 1) {
        for (unsigned j = k >> 1; j > 0; j >>= 1) {
            __syncthreads();
            #pragma unroll
            for (int b = 0; b < SORTN / 256; ++b) {
                const unsigned i = (unsigned)t + 256u * b;
                const unsigned p = i ^ j;
                if (p > i) {
                    const unsigned a = keys[i], c = keys[p];
                    const bool up = ((i & k) == 0);
                    if ((a > c) == up) { keys[i] = c; keys[p] = a; }
                }
            }
        }
    }
    __syncthreads();

    const float4 qv0 = *(const float4*)(&q_lds[0][lane * 4]);
    const float4 qv1 = *(const float4*)(&q_lds[1][lane * 4]);

    // ---- sorted gather stream, 2-deep pipeline ----
    int pos = hw;
    unsigned key = keys[pos];
    float4 e;
    if (key != SENT)
        e = ((const float4*)(table + (size_t)(key >> 10) * DIMS))[lane];
    pos += 8;
    while (key != SENT) {
        const unsigned nkey = (pos < SORTN) ? keys[pos] : SENT;
        float4 en;
        if (nkey != SENT)   // issue next gather BEFORE reducing current
            en = ((const float4*)(table + (size_t)(nkey >> 10) * DIMS))[lane];
        const int r = (key >> 9) & 1;
        const int j = key & 511;
        const float4 qv = r ? qv1 : qv0;
        float dq = qv.x*e.x + qv.y*e.y + qv.z*e.z + qv.w*e.w;
        float de = e.x*e.x + e.y*e.y + e.z*e.z + e.w*e.w;
        dq += __shfl_xor(dq, 16, 64); de += __shfl_xor(de, 16, 64);
        dq += __shfl_xor(dq, 8, 64);  de += __shfl_xor(de, 8, 64);
        float v = (lane & 8) ? de : dq;
        v += __shfl_xor(v, 1, 64);
        v += __shfl_xor(v, 2, 64);
        v += __shfl_xor(v, 4, 64);
        const float u = __shfl_xor(v, 8, 64);
        if (lane == 0) logits[r][j] = v / fmaxf(sqrtf(u), EPSN) * INV_TEMP;
        key = nkey; e = en; pos += 8;
    }
    __syncthreads();

    // ---- stable LSE per row over 257 logits ----
    #pragma unroll 1
    for (int r = 0; r < 2; ++r) {
        if (r ? !v1 : !v0) continue;    // block-uniform
        float mx = logits[r][t];
        if (t == 0) mx = fmaxf(mx, logits[r][KNEG]);
        #pragma unroll
        for (int m = 1; m < 64; m <<= 1) mx = fmaxf(mx, __shfl_xor(mx, m, 64));
        if ((t & 63) == 0) red[t >> 6] = mx;
        __syncthreads();
        if (t == 0) red[4] = fmaxf(fmaxf(red[0], red[1]), fmaxf(red[2], red[3]));
        __syncthreads();
        mx = red[4];

        float pp = expf(logits[r][t] - mx);
        if (t == 0) pp += expf(logits[r][KNEG] - mx);
        #pragma unroll
        for (int m = 1; m < 64; m <<= 1) pp += __shfl_xor(pp, m, 64);
        if ((t & 63) == 0) red[t >> 6] = pp;
        __syncthreads();
        if (t == 0) {
            const float s   = red[0] + red[1] + red[2] + red[3];
            const float lse = mx + logf(s);
            loss_out[r ? n1 : n0] = (lse - logits[r][0]) * (r ? w1 : w0);
        }
        __syncthreads();
    }
}

// Deterministic final reduction: sum(loss*w) / sum(w)
__global__ __launch_bounds__(256) void ssl_reduce_kernel(
    const float* __restrict__ loss,  // [N]
    const float* __restrict__ w,     // [N]
    float* __restrict__ out, int n)
{
    __shared__ float red[8];
    const int t = threadIdx.x;
    float sl = 0.0f, sw = 0.0f;
    for (int i = t; i < n; i += 256) { sl += loss[i]; sw += w[i]; }
    #pragma unroll
    for (int m = 1; m < 64; m <<= 1) {
        sl += __shfl_xor(sl, m, 64);
        sw += __shfl_xor(sw, m, 64);
    }
    if ((t & 63) == 0) { red[t >> 6] = sl; red[4 + (t >> 6)] = sw; }
    __syncthreads();
    if (t == 0) {
        const float SL = red[0] + red[1] + red[2] + red[3];
        const float SW = red[4] + red[5] + red[6] + red[7];
        out[0] = SL / SW;
    }
}

extern "C" void kernel_launch(void* const* d_in, const int* in_sizes, int n_in,
                              void* d_out, int out_size, void* d_ws, size_t ws_size,
                              hipStream_t stream) {
    const float* out_emb = (const float*)d_in[0];   // [16,256,128]
    const float* table   = (const float*)d_in[1];   // [1000001,128]
    const float* w       = (const float*)d_in[2];   // [16,256]
    const int*   tgt     = (const int*)d_in[3];     // [16,256]
    const int*   negs    = (const int*)d_in[4];     // [4096,256]

    const int N = in_sizes[2];                       // 4096
    const int rows = in_sizes[1] / DIMS;             // 1000001
    const int max_row = rows - 1;

    float* loss_ws = (float*)d_ws;                   // N floats

    ssl_sorted_kernel<<<N / 2, 256, 0, stream>>>(out_emb, table, w, tgt, negs,
                                                 loss_ws, N, max_row);
    ssl_reduce_kernel<<<1, 256, 0, stream>>>(loss_ws, w, (float*)d_out, N);
}

// Round 6
// 83.785 us; speedup vs baseline: 2.9076x; 1.5192x over previous
//
#include <hip/hip_runtime.h>
#include <math.h>

#define DIMS 128
#define KNEG 256
#define INV_TEMP 20.0f   // 1 / 0.05
#define EPSN 1e-12f

// One block (256 threads = 8 half-waves of 32 lanes) per output row n.
// Each half-wave gathers one candidate item row (512 B) with a single
// coalesced float4-per-lane load, computes dot(q,e) and dot(e,e) together
// (on-the-fly normalization of the table row), reduces across 32 lanes.
// R1-R5 established: this simple structure is within ~18% of streaming BW
// on a random-gather pattern whose unique working set (333 MB) exceeds L3;
// ILP, pass-partitioning, and sort-sweep variants were all neutral/worse.
__global__ __launch_bounds__(256) void ssl_row_kernel(
    const float* __restrict__ out_emb,   // [N, 128]
    const float* __restrict__ table,     // [M, 128] raw (unnormalized)
    const float* __restrict__ w,         // [N]
    const int*   __restrict__ tgt,       // [N]
    const int*   __restrict__ negs,      // [N, 256]
    float*       __restrict__ loss_out,  // [N] = loss_per * w
    int max_row)                         // = M-1 (clip bound)
{
    const int n = blockIdx.x;
    const int t = threadIdx.x;

    __shared__ __align__(16) float q_lds[DIMS];
    __shared__ float logits[KNEG + 1];
    __shared__ int   nid[KNEG];
    __shared__ float red[8];

    const float wn = w[n];
    if (wn == 0.0f) {            // w==0 rows contribute 0 to the weighted sum
        if (t == 0) loss_out[n] = 0.0f;
        return;
    }

    // ---- normalize q row into LDS ----
    float x = 0.0f;
    if (t < DIMS) x = out_emb[(size_t)n * DIMS + t];
    float ss = x * x;
    #pragma unroll
    for (int m = 1; m < 64; m <<= 1) ss += __shfl_xor(ss, m, 64);
    if ((t & 63) == 0) red[t >> 6] = ss;
    if (t < KNEG) nid[t] = negs[(size_t)n * KNEG + t];
    __syncthreads();
    const float inv_qn = 1.0f / fmaxf(sqrtf(red[0] + red[1]), EPSN);
    if (t < DIMS) q_lds[t] = x * inv_qn;
    __syncthreads();

    // ---- gather + logits ----
    const int hw   = t >> 5;   // half-wave id 0..7
    const int lane = t & 31;   // lane in half-wave
    const float4 qv = *(const float4*)(q_lds + lane * 4);
    const int tgtn = tgt[n];

    #pragma unroll 1
    for (int k = 0; k < 32; k += 2) {
        const int j1 = hw + (k << 3);
        const int j2 = j1 + 8;
        int id1 = (j1 == 0) ? tgtn : nid[j1 - 1];
        int id2 = nid[j2 - 1];
        int i1 = id1 - 1; i1 = i1 < 0 ? 0 : (i1 > max_row ? max_row : i1);
        int i2 = id2 - 1; i2 = i2 < 0 ? 0 : (i2 > max_row ? max_row : i2);
        const float4 e1 = ((const float4*)(table + (size_t)i1 * DIMS))[lane];
        const float4 e2 = ((const float4*)(table + (size_t)i2 * DIMS))[lane];
        float dq1 = qv.x*e1.x + qv.y*e1.y + qv.z*e1.z + qv.w*e1.w;
        float de1 = e1.x*e1.x + e1.y*e1.y + e1.z*e1.z + e1.w*e1.w;
        float dq2 = qv.x*e2.x + qv.y*e2.y + qv.z*e2.z + qv.w*e2.w;
        float de2 = e2.x*e2.x + e2.y*e2.y + e2.z*e2.z + e2.w*e2.w;
        #pragma unroll
        for (int m = 1; m < 32; m <<= 1) {
            dq1 += __shfl_xor(dq1, m, 64);
            de1 += __shfl_xor(de1, m, 64);
            dq2 += __shfl_xor(dq2, m, 64);
            de2 += __shfl_xor(de2, m, 64);
        }
        if (lane == 0) {
            logits[j1] = dq1 / fmaxf(sqrtf(de1), EPSN) * INV_TEMP;
            logits[j2] = dq2 / fmaxf(sqrtf(de2), EPSN) * INV_TEMP;
        }
    }
    if (hw == 0) {   // j = 256 (last negative)
        int id = nid[KNEG - 1];
        int i1 = id - 1; i1 = i1 < 0 ? 0 : (i1 > max_row ? max_row : i1);
        const float4 e1 = ((const float4*)(table + (size_t)i1 * DIMS))[lane];
        float dq1 = qv.x*e1.x + qv.y*e1.y + qv.z*e1.z + qv.w*e1.w;
        float de1 = e1.x*e1.x + e1.y*e1.y + e1.z*e1.z + e1.w*e1.w;
        #pragma unroll
        for (int m = 1; m < 32; m <<= 1) {
            dq1 += __shfl_xor(dq1, m, 64);
            de1 += __shfl_xor(de1, m, 64);
        }
        if (lane == 0) logits[KNEG] = dq1 / fmaxf(sqrtf(de1), EPSN) * INV_TEMP;
    }
    __syncthreads();

    // ---- stable LSE over 257 logits ----
    float mx = logits[t];
    if (t == 0) mx = fmaxf(mx, logits[KNEG]);
    #pragma unroll
    for (int m = 1; m < 64; m <<= 1) mx = fmaxf(mx, __shfl_xor(mx, m, 64));
    if ((t & 63) == 0) red[t >> 6] = mx;
    __syncthreads();
    if (t == 0) red[4] = fmaxf(fmaxf(red[0], red[1]), fmaxf(red[2], red[3]));
    __syncthreads();
    mx = red[4];

    float p = expf(logits[t] - mx);
    if (t == 0) p += expf(logits[KNEG] - mx);
    #pragma unroll
    for (int m = 1; m < 64; m <<= 1) p += __shfl_xor(p, m, 64);
    if ((t & 63) == 0) red[t >> 6] = p;
    __syncthreads();
    if (t == 0) {
        const float s   = red[0] + red[1] + red[2] + red[3];
        const float lse = mx + logf(s);
        loss_out[n] = (lse - logits[0]) * wn;   // loss_per * w
    }
}

// Deterministic final reduction: sum(loss*w) / sum(w)
__global__ __launch_bounds__(256) void ssl_reduce_kernel(
    const float* __restrict__ loss,  // [N]
    const float* __restrict__ w,     // [N]
    float* __restrict__ out, int n)
{
    __shared__ float red[8];
    const int t = threadIdx.x;
    float sl = 0.0f, sw = 0.0f;
    for (int i = t; i < n; i += 256) { sl += loss[i]; sw += w[i]; }
    #pragma unroll
    for (int m = 1; m < 64; m <<= 1) {
        sl += __shfl_xor(sl, m, 64);
        sw += __shfl_xor(sw, m, 64);
    }
    if ((t & 63) == 0) { red[t >> 6] = sl; red[4 + (t >> 6)] = sw; }
    __syncthreads();
    if (t == 0) {
        const float SL = red[0] + red[1] + red[2] + red[3];
        const float SW = red[4] + red[5] + red[6] + red[7];
        out[0] = SL / SW;
    }
}

extern "C" void kernel_launch(void* const* d_in, const int* in_sizes, int n_in,
                              void* d_out, int out_size, void* d_ws, size_t ws_size,
                              hipStream_t stream) {
    const float* out_emb = (const float*)d_in[0];   // [16,256,128]
    const float* table   = (const float*)d_in[1];   // [1000001,128]
    const float* w       = (const float*)d_in[2];   // [16,256]
    const int*   tgt     = (const int*)d_in[3];     // [16,256]
    const int*   negs    = (const int*)d_in[4];     // [4096,256]

    const int N = in_sizes[2];                       // 4096
    const int rows = in_sizes[1] / DIMS;             // 1000001
    const int max_row = rows - 1;

    float* loss_ws = (float*)d_ws;                   // N floats

    ssl_row_kernel<<<N, 256, 0, stream>>>(out_emb, table, w, tgt, negs, loss_ws, max_row);
    ssl_reduce_kernel<<<1, 256, 0, stream>>>(loss_ws, w, (float*)d_out, N);
}